// Round 8
// baseline (181.439 us; speedup 1.0000x reference)
//
#include <hip/hip_runtime.h>
#include <hip/hip_bf16.h>

#define NH 4
#define NB 32
#define NT 1500
#define NE 512
#define ND 512
#define NA 256
#define NC 10
#define NKS 100
#define NKW 201
#define NO 512
#define NBT (NB*NT)   // 48000
#define RB 375        // row blocks of 128
#define OSPLIT 16     // k_out i-chunks

// fused prep block ranges
#define PE_BLKS 3000          // prep_enc: RB*8
#define PW_BLKS 2176          // prep_w
#define CV_BLKS 1024          // conv: hb(128) x chunk(8)
#define DP_BLKS 512           // dproj: hb(128) x dc(4)
#define PREP_BLKS (PE_BLKS + PW_BLKS + CV_BLKS + DP_BLKS)

typedef unsigned short u16;
typedef unsigned int u32;
typedef __attribute__((ext_vector_type(8))) short short8;
typedef __attribute__((ext_vector_type(4))) float f32x4;

__device__ __forceinline__ u16 f2bf(float f) {
  u32 x = __builtin_bit_cast(u32, f);
  return (u16)((x + 0x7FFFu + ((x >> 16) & 1u)) >> 16);
}

__device__ __forceinline__ float bf2f(u16 b) {
  return __builtin_bit_cast(float, (u32)b << 16);
}

__device__ __forceinline__ void gld_lds16(const void* g, void* l) {
  __builtin_amdgcn_global_load_lds((const __attribute__((address_space(1))) u32*)g,
                                   (__attribute__((address_space(3))) u32*)l, 16, 0, 0);
}

// tanh(x) = 1 - 2/(exp2(2*log2e*x)+1); exact at +-inf, err ~2e-6
__device__ __forceinline__ float fast_tanh(float x) {
  float t, r;
  asm("v_exp_f32 %0, %1" : "=v"(t) : "v"(x * 2.885390082f));
  asm("v_rcp_f32 %0, %1" : "=v"(r) : "v"(t + 1.0f));
  return __builtin_fmaf(-2.0f, r, 1.0f);
}

// ---- fused prep: enc pack | W pack | conv | dproj(split-D) ----
// manual LDS union: conv needs 18880 B (max branch)
__global__ __launch_bounds__(256) void k_prep(
    const float* __restrict__ in,        // enc
    const float* __restrict__ We, const float* __restrict__ Wa,
    const float* __restrict__ att, const float* __restrict__ cw,
    const float* __restrict__ dz, const float* __restrict__ wd,
    const float* __restrict__ be,
    u16* __restrict__ encp, u16* __restrict__ wc,
    u16* __restrict__ cvb, float* __restrict__ pdp) {
  const int bid = blockIdx.x;
  const int tid = threadIdx.x;
  __shared__ __align__(16) char smem[18944];

  if (bid < PE_BLKS) {
    // ---- enc fp32 -> bf16 packed: encp[rowblk][kc(64)][m(128)][8] ----
    // conflict-free: 16B LDS slots (2-way quarter-wave), rotated copy-out (2-way)
    u16* tile = (u16*)smem;             // [kcl(8)][m(128)][8] = 16 KB
    const int rowblk = bid >> 3;
    const int ks = bid & 7;
    const int r = tid >> 1;             // 0..127
    const int part = tid & 1;           // k-half (32 k each)
    const float* src = in + ((size_t)(rowblk * 128 + r)) * NE + ks * 64 + part * 32;
#pragma unroll
    for (int q = 0; q < 4; ++q) {       // kcl = part*4 + q
      float4 v0 = ((const float4*)src)[q * 2];
      float4 v1 = ((const float4*)src)[q * 2 + 1];
      short8 s;
      s[0] = (short)f2bf(v0.x); s[1] = (short)f2bf(v0.y);
      s[2] = (short)f2bf(v0.z); s[3] = (short)f2bf(v0.w);
      s[4] = (short)f2bf(v1.x); s[5] = (short)f2bf(v1.y);
      s[6] = (short)f2bf(v1.z); s[7] = (short)f2bf(v1.w);
      *(short8*)&tile[((part * 4 + q) * 128 + r) * 8] = s;
    }
    __syncthreads();
    u16* ob = encp + ((size_t)rowblk * 64 + ks * 8) * 1024;
#pragma unroll
    for (int i = 0; i < 4; ++i) {
      int ii = (i + (tid >> 1)) & 3;    // rotate chunks -> 2-way LDS read
      int o = tid * 32 + ii * 8;        // u16 units (64B/thread total)
      *(uint4*)(ob + o) = *(const uint4*)(tile + o);
    }
  } else if (bid < PE_BLKS + PW_BLKS) {
    // ---- W pack: wc[H][kc(68)][n(256)][8] ----
    int idx = (bid - PE_BLKS) * 256 + tid;
    int h = idx / 139264;
    int r = idx % 139264;
    int kc = r / 2048; r %= 2048;
    int n = r / 8;
    int j = r % 8;
    int k = kc * 8 + j;
    float v = 0.f;
    if (k < NE) v = We[((size_t)h * NE + k) * NA + n];
    else if (k - NE < NC) v = Wa[((size_t)h * NC + (k - NE)) * NA + n];
    wc[idx] = f2bf(v);
  } else if (bid < PE_BLKS + PW_BLKS + CV_BLKS) {
    // ---- location conv -> packed tail ----
    float* al = (float*)smem;                  // 6000 B
    float* klT = (float*)(smem + 6016);        // 12864 B
    int id = bid - (PE_BLKS + PW_BLKS);
    int hb = id >> 3;
    int h = hb >> 5, b = hb & 31;
    int chunk = id & 7;
    for (int i = tid; i < NT; i += 256) al[i] = att[(size_t)hb * NT + i];
    for (int i = tid; i < NC * NKW; i += 256)
      klT[(i % NKW) * 16 + (i / NKW)] = cw[h * NC * NKW + i];
    __syncthreads();
    int start = chunk * 188;
    int len = min(188, NT - start);
    if (tid < len) {
      int t = start + tid;
      float acc[NC];
#pragma unroll
      for (int c = 0; c < NC; ++c) acc[c] = 0.f;
      int kmin = max(0, NKS - t);
      int kmax = min(NKW - 1, NT - 1 + NKS - t);
      for (int k = kmin; k <= kmax; ++k) {
        float a = al[t + k - NKS];
        float4 w0 = *(const float4*)&klT[k * 16];
        float4 w1 = *(const float4*)&klT[k * 16 + 4];
        float2 w2 = *(const float2*)&klT[k * 16 + 8];
        acc[0] += a * w0.x; acc[1] += a * w0.y; acc[2] += a * w0.z; acc[3] += a * w0.w;
        acc[4] += a * w1.x; acc[5] += a * w1.y; acc[6] += a * w1.z; acc[7] += a * w1.w;
        acc[8] += a * w2.x; acc[9] += a * w2.y;
      }
      int row = b * NT + t;
      u16* o = cvb + ((size_t)(h * RB) + (row >> 7)) * 4096 + (row & 127) * 8;
      short8 g0, g1, gz;
#pragma unroll
      for (int c = 0; c < 8; ++c) g0[c] = (short)f2bf(acc[c]);
      g1[0] = (short)f2bf(acc[8]); g1[1] = (short)f2bf(acc[9]);
#pragma unroll
      for (int c = 2; c < 8; ++c) g1[c] = 0;
#pragma unroll
      for (int c = 0; c < 8; ++c) gz[c] = 0;
      *(short8*)&o[0]    = g0;
      *(short8*)&o[1024] = g1;
      *(short8*)&o[2048] = gz;
      *(short8*)&o[3072] = gz;
    }
  } else {
    // ---- dproj split-D: pdp[dc][h][b][a] ----
    float* z = (float*)smem;
    int id = bid - (PE_BLKS + PW_BLKS + CV_BLKS);
    int hb = id >> 2, dc = id & 3;
    int h = hb >> 5, b = hb & 31;
    if (tid < 128) z[tid] = dz[b * ND + dc * 128 + tid];
    __syncthreads();
    float s = (dc == 0) ? be[h * NA + tid] : 0.f;
    const float* wp = wd + ((size_t)h * ND + dc * 128) * NA + tid;
    for (int d = 0; d < 128; ++d) s += z[d] * wp[(size_t)d * NA];
    pdp[(((size_t)dc * NH + h) * NB + b) * NA + tid] = s;
  }
}

// ---- fused GEMM + bias + tanh + gvec reduce -> e[h][b*T+t] ----
// tile 128 rows x 256 cols, BK=32 x 17 steps, 3-buffer counted-vmcnt pipeline
__global__ __launch_bounds__(512) void k_gemm_e(
    const u16* __restrict__ encp, const u16* __restrict__ cvb,
    const u16* __restrict__ wcomb, const float* __restrict__ pdp,
    const float* __restrict__ gvec, float* __restrict__ ebuf) {
  // bijective XCD chunk swizzle (nwg=1500, q=187, r=4), head fastest
  const int orig = blockIdx.x;
  const int xcd = orig & 7, pos = orig >> 3;
  const int wgid = (xcd < 4 ? xcd * 188 : 752 + (xcd - 4) * 187) + pos;
  const int h = wgid & 3;
  const int rowblk = wgid >> 2;
  const int row0 = rowblk * 128;
  const int tid = threadIdx.x;
  const int lane = tid & 63;
  const int wid = tid >> 6;
  const int wm = wid >> 2;   // 0..1  (rows)
  const int wn = wid & 3;    // 0..3  (cols)
  const int l16 = lane & 15;
  const int lh = lane >> 4;

  __shared__ u16 Alds[3][4096];    // [kc(4)][m(128)][8]
  __shared__ u16 Blds[3][8192];    // [kc(4)][n(256)][8]
  __shared__ float dp[2][NA];
  __shared__ float gl[NA];
  __shared__ float elds[128][4];

  const int b0 = row0 / NT;
  const int bound = (b0 + 1) * NT - row0;   // local row where b increments
  const int b1 = min(b0 + 1, NB - 1);
  if (tid < NA) {
    float s = 0.f;
#pragma unroll
    for (int dc = 0; dc < 4; ++dc)
      s += pdp[(((size_t)dc * NH + h) * NB + b0) * NA + tid];
    dp[0][tid] = s;
    gl[tid] = gvec[h * NA + tid];
  } else {
    int a = tid - NA;
    float s = 0.f;
#pragma unroll
    for (int dc = 0; dc < 4; ++dc)
      s += pdp[(((size_t)dc * NH + h) * NB + b1) * NA + a];
    dp[1][a] = s;
  }

  f32x4 acc[4][4] = {};

  const u16* aSrc = encp + (size_t)rowblk * 65536;   // [64 kc][128][8]
  const u16* bSrc = wcomb + (size_t)h * 139264;      // [68 kc][256][8]
  const u16* aTail = cvb + ((size_t)(h * RB) + rowblk) * 4096;

  const int arow = wm * 64 + l16;
  const int bcol = wn * 64 + l16;

#define ISSUE(is, buf) do {                                         \
    const u16* ga_ = ((is) < 16) ? (aSrc + (is) * 4096) : aTail;    \
    gld_lds16(ga_ + tid * 8, &Alds[(buf)][tid * 8]);                \
    const u16* gb_ = bSrc + (is) * 8192;                            \
    gld_lds16(gb_ + tid * 8, &Blds[(buf)][tid * 8]);                \
    gld_lds16(gb_ + 4096 + tid * 8, &Blds[(buf)][4096 + tid * 8]);  \
  } while (0)

  // prologue: depth-2 prefetch
  ISSUE(0, 0);
  ISSUE(1, 1);

  int cur = 0;
  for (int ks = 0; ks < 17; ++ks) {
    // wait for step ks's 3 loads (the next step's 3 stay in flight)
    if (ks < 16) asm volatile("s_waitcnt vmcnt(3)" ::: "memory");
    else         asm volatile("s_waitcnt vmcnt(0)" ::: "memory");
    __builtin_amdgcn_s_barrier();
    __builtin_amdgcn_sched_barrier(0);
    if (ks + 2 <= 16) {
      int nbuf = (cur + 2 >= 3) ? cur - 1 : cur + 2;
      ISSUE(ks + 2, nbuf);
    }
    const u16* ap = &Alds[cur][(lh * 128 + arow) * 8];
    const u16* bp = &Blds[cur][(lh * 256 + bcol) * 8];
    short8 af[4], bf4[4];
#pragma unroll
    for (int i = 0; i < 4; ++i) af[i] = *(const short8*)&ap[i * 128];
#pragma unroll
    for (int i = 0; i < 4; ++i) bf4[i] = *(const short8*)&bp[i * 128];
    __builtin_amdgcn_s_setprio(1);
#pragma unroll
    for (int i = 0; i < 4; ++i)
#pragma unroll
      for (int j = 0; j < 4; ++j)
        acc[i][j] = __builtin_amdgcn_mfma_f32_16x16x32_bf16(af[i], bf4[j], acc[i][j], 0, 0, 0);
    __builtin_amdgcn_s_setprio(0);
    cur = (cur == 2) ? 0 : cur + 1;
  }
#undef ISSUE
  __syncthreads();

  // epilogue: bias + fast_tanh + g-weighted col-reduce
  float ep[4][4];
#pragma unroll
  for (int i = 0; i < 4; ++i)
#pragma unroll
    for (int r = 0; r < 4; ++r) ep[i][r] = 0.f;

#pragma unroll
  for (int j = 0; j < 4; ++j) {   // col frag
    int col = wn * 64 + j * 16 + l16;
    float g = gl[col];
    float biasLo = dp[0][col], biasHi = dp[1][col];
#pragma unroll
    for (int i = 0; i < 4; ++i) {
#pragma unroll
      for (int r = 0; r < 4; ++r) {
        int rl = wm * 64 + i * 16 + lh * 4 + r;
        float bias = (rl >= bound) ? biasHi : biasLo;
        ep[i][r] += g * fast_tanh(acc[i][j][r] + bias);
      }
    }
  }
#pragma unroll
  for (int d = 1; d < 16; d <<= 1)
#pragma unroll
    for (int i = 0; i < 4; ++i)
#pragma unroll
      for (int r = 0; r < 4; ++r) ep[i][r] += __shfl_xor(ep[i][r], d, 64);

  if (l16 == 0) {
#pragma unroll
    for (int i = 0; i < 4; ++i)
#pragma unroll
      for (int r = 0; r < 4; ++r) elds[wm * 64 + i * 16 + lh * 4 + r][wn] = ep[i][r];
  }
  __syncthreads();
  if (tid < 128) {
    float e = elds[tid][0] + elds[tid][1] + elds[tid][2] + elds[tid][3];
    ebuf[(size_t)h * NBT + row0 + tid] = e;
  }
}

// ---- context with inline softmax: writes wout chunk + part[ch][h][b][e] ----
__global__ __launch_bounds__(512) void k_context(const u16* __restrict__ encp,
                                                 const float* __restrict__ ebuf,
                                                 float* __restrict__ wout,
                                                 float* __restrict__ part) {
  int b = blockIdx.x, ch = blockIdx.y;
  int tid = threadIdx.x;
  int g = tid >> 6;        // 0..7 t-subgroup
  int lane = tid & 63;     // e-chunk: e = lane*8 .. lane*8+7
  __shared__ float el[NH][NT];     // 24 KB
  __shared__ float wl[NH][192];    // 3 KB
  __shared__ float redw[NH][8];

#pragma unroll
  for (int hh = 0; hh < NH; ++hh)
    for (int t = tid; t < NT; t += 512)
      el[hh][t] = ebuf[((size_t)hh * NB + b) * NT + t];
  __syncthreads();

  // per-row max
  float mx[NH];
#pragma unroll
  for (int hh = 0; hh < NH; ++hh) {
    float m = -1e30f;
    for (int t = tid; t < NT; t += 512) m = fmaxf(m, el[hh][t]);
#pragma unroll
    for (int d = 1; d < 64; d <<= 1) m = fmaxf(m, __shfl_xor(m, d, 64));
    if (lane == 0) redw[hh][g] = m;
  }
  __syncthreads();
#pragma unroll
  for (int hh = 0; hh < NH; ++hh) {
    float m = redw[hh][0];
#pragma unroll
    for (int i = 1; i < 8; ++i) m = fmaxf(m, redw[hh][i]);
    mx[hh] = m;
  }
  __syncthreads();
  // per-row sum
  float inv[NH];
#pragma unroll
  for (int hh = 0; hh < NH; ++hh) {
    float s = 0.f;
    for (int t = tid; t < NT; t += 512) s += expf(2.f * (el[hh][t] - mx[hh]));
#pragma unroll
    for (int d = 1; d < 64; d <<= 1) s += __shfl_xor(s, d, 64);
    if (lane == 0) redw[hh][g] = s;
  }
  __syncthreads();
#pragma unroll
  for (int hh = 0; hh < NH; ++hh) {
    float s = redw[hh][0];
#pragma unroll
    for (int i = 1; i < 8; ++i) s += redw[hh][i];
    inv[hh] = 1.f / s;
  }

  int c0 = ch * 188;
  int n = min(188, NT - c0);
#pragma unroll
  for (int hh = 0; hh < NH; ++hh) {
    for (int tt = tid; tt < 188; tt += 512) {
      float w = 0.f;
      if (tt < n) {
        w = expf(2.f * (el[hh][c0 + tt] - mx[hh])) * inv[hh];
        wout[((size_t)hh * NB + b) * NT + c0 + tt] = w;
      }
      wl[hh][tt] = w;
    }
  }
  __syncthreads();

  float acc[NH][8];
#pragma unroll
  for (int hh = 0; hh < NH; ++hh)
#pragma unroll
    for (int j = 0; j < 8; ++j) acc[hh][j] = 0.f;

  for (int tt = g; tt < n; tt += 8) {
    int row = b * NT + c0 + tt;
    const u16* src = encp + ((size_t)(row >> 7)) * 65536 + lane * 1024 + (row & 127) * 8;
    short8 v = *(const short8*)src;
    float f[8];
#pragma unroll
    for (int j = 0; j < 8; ++j) f[j] = bf2f((u16)v[j]);
#pragma unroll
    for (int hh = 0; hh < NH; ++hh) {
      float ww = wl[hh][tt];
#pragma unroll
      for (int j = 0; j < 8; ++j) acc[hh][j] += ww * f[j];
    }
  }
  __shared__ float red[8][NE];   // 16 KB
#pragma unroll
  for (int hh = 0; hh < NH; ++hh) {
    __syncthreads();
#pragma unroll
    for (int j = 0; j < 8; ++j) red[g][lane * 8 + j] = acc[hh][j];
    __syncthreads();
    float s = red[0][tid] + red[1][tid] + red[2][tid] + red[3][tid]
            + red[4][tid] + red[5][tid] + red[6][tid] + red[7][tid];
    part[((size_t)(ch * NH + hh) * NB + b) * NE + tid] = s;
  }
}

// ---- out projection partials: pout[is][b][o] over i-chunk of 128 ----
__global__ __launch_bounds__(512) void k_out_part(const float* __restrict__ part,
                                                  const float* __restrict__ Wo,
                                                  float* __restrict__ pout) {
  int b = blockIdx.x, is = blockIdx.y;
  int tid = threadIdx.x;
  int i0 = is * 128;
  __shared__ float cc[128];
  if (tid < 128) {
    int i = i0 + tid;
    int hh = i >> 9, ee = i & 511;
    float s = 0.f;
#pragma unroll
    for (int ch = 0; ch < 8; ++ch)
      s += part[((size_t)(ch * NH + hh) * NB + b) * NE + ee];
    cc[tid] = s;
  }
  __syncthreads();
  float acc = 0.f;
  const float* wp = Wo + (size_t)i0 * NO + tid;
#pragma unroll 4
  for (int il = 0; il < 128; il += 4) {
    float4 v = *(const float4*)&cc[il];
    acc += v.x * wp[(size_t)(il + 0) * NO];
    acc += v.y * wp[(size_t)(il + 1) * NO];
    acc += v.z * wp[(size_t)(il + 2) * NO];
    acc += v.w * wp[(size_t)(il + 3) * NO];
  }
  pout[((size_t)is * NB + b) * NO + tid] = acc;
}

// ---- reduce out partials + bias ----
__global__ __launch_bounds__(512) void k_out_red(const float* __restrict__ pout,
                                                 const float* __restrict__ bo,
                                                 float* __restrict__ cout) {
  int b = blockIdx.x, tid = threadIdx.x;
  float acc = bo[tid];
#pragma unroll
  for (int is = 0; is < OSPLIT; ++is)
    acc += pout[((size_t)is * NB + b) * NO + tid];
  cout[(size_t)b * NO + tid] = acc;
}

extern "C" void kernel_launch(void* const* d_in, const int* in_sizes, int n_in,
                              void* d_out, int out_size, void* d_ws, size_t ws_size,
                              hipStream_t stream) {
  const float* enc      = (const float*)d_in[0];
  const float* dec_z    = (const float*)d_in[2];
  const float* att_prev = (const float*)d_in[3];
  const float* W_enc    = (const float*)d_in[4];
  const float* b_enc    = (const float*)d_in[5];
  const float* W_dec    = (const float*)d_in[6];
  const float* W_att    = (const float*)d_in[7];
  const float* conv_w   = (const float*)d_in[8];
  const float* gvec_w   = (const float*)d_in[9];
  const float* W_o      = (const float*)d_in[10];
  const float* b_o      = (const float*)d_in[11];
  float* cout = (float*)d_out;                 // [B,O]
  float* wout = (float*)d_out + NB * NO;       // [H,B,T]

  char* ws = (char*)d_ws;
  size_t off = 0;
  u16* encp   = (u16*)(ws + off); off += (size_t)NBT * NE * 2;          // 49.2 MB
  u16* cvb    = (u16*)(ws + off); off += (size_t)NH * RB * 4096 * 2;    // 12.3 MB
  u16* wcomb  = (u16*)(ws + off); off += (size_t)NH * 139264 * 2;       // 1.1 MB
  float* pdp   = (float*)(ws + off); off += (size_t)4 * NH * NB * NA * 4;
  float* ebuf  = (float*)(ws + off); off += (size_t)NH * NB * NT * 4;
  float* part  = (float*)(ws + off); off += (size_t)8 * NH * NB * NE * 4;
  float* pout  = (float*)(ws + off); off += (size_t)OSPLIT * NB * NO * 4;

  hipLaunchKernelGGL(k_prep, dim3(PREP_BLKS), dim3(256), 0, stream,
                     enc, W_enc, W_att, att_prev, conv_w, dec_z, W_dec, b_enc,
                     encp, wcomb, cvb, pdp);
  hipLaunchKernelGGL(k_gemm_e, dim3(1500), dim3(512), 0, stream,
                     encp, cvb, wcomb, pdp, gvec_w, ebuf);
  hipLaunchKernelGGL(k_context, dim3(32, 8), dim3(512), 0, stream,
                     encp, ebuf, wout, part);
  hipLaunchKernelGGL(k_out_part, dim3(NB, OSPLIT), dim3(512), 0, stream, part, W_o, pout);
  hipLaunchKernelGGL(k_out_red, dim3(NB), dim3(512), 0, stream, pout, b_o, cout);
}

// Round 9
// 132.401 us; speedup vs baseline: 1.3704x; 1.3704x over previous
//
#include <hip/hip_runtime.h>
#include <hip/hip_bf16.h>

#define NH 4
#define NB 32
#define NT 1500
#define NE 512
#define ND 512
#define NA 256
#define NC 10
#define NKS 100
#define NKW 201
#define NO 512
#define NBT (NB*NT)   // 48000
#define RB 375        // row blocks of 128
#define OSPLIT 16     // k_out i-chunks

// fused prep block ranges: small latency jobs first, streaming cast last
#define CV_BLKS 1024          // conv: hb(128) x chunk(8)
#define DP_BLKS 512           // dproj: hb(128) x dc(4)
#define PW_BLKS 2176          // W pack
#define PE_BLKS 6000          // enc cast: 24.576M floats / (256*16)
#define PREP_BLKS (CV_BLKS + DP_BLKS + PW_BLKS + PE_BLKS)

typedef unsigned short u16;
typedef unsigned int u32;
typedef __attribute__((ext_vector_type(8))) short short8;
typedef __attribute__((ext_vector_type(4))) float f32x4;

__device__ __forceinline__ u16 f2bf(float f) {
  u32 x = __builtin_bit_cast(u32, f);
  return (u16)((x + 0x7FFFu + ((x >> 16) & 1u)) >> 16);
}

__device__ __forceinline__ float bf2f(u16 b) {
  return __builtin_bit_cast(float, (u32)b << 16);
}

__device__ __forceinline__ void gld_lds16(const void* g, void* l) {
  __builtin_amdgcn_global_load_lds((const __attribute__((address_space(1))) u32*)g,
                                   (__attribute__((address_space(3))) u32*)l, 16, 0, 0);
}

// tanh(x) = 1 - 2/(exp2(2*log2e*x)+1); exact at +-inf, err ~2e-6
__device__ __forceinline__ float fast_tanh(float x) {
  float t, r;
  asm("v_exp_f32 %0, %1" : "=v"(t) : "v"(x * 2.885390082f));
  asm("v_rcp_f32 %0, %1" : "=v"(r) : "v"(t + 1.0f));
  return __builtin_fmaf(-2.0f, r, 1.0f);
}

// ---- fused prep: conv | dproj | W pack | enc cast (row-major bf16) ----
__global__ __launch_bounds__(256) void k_prep(
    const float* __restrict__ in,        // enc
    const float* __restrict__ We, const float* __restrict__ Wa,
    const float* __restrict__ att, const float* __restrict__ cw,
    const float* __restrict__ dz, const float* __restrict__ wd,
    const float* __restrict__ be,
    u16* __restrict__ encb, u16* __restrict__ wc,
    u16* __restrict__ cvb, float* __restrict__ pdp) {
  const int bid = blockIdx.x;
  const int tid = threadIdx.x;
  __shared__ __align__(16) char smem[18944];

  if (bid < CV_BLKS) {
    // ---- location conv -> row-major tail: cvb[h*NBT+row][32] ----
    float* al = (float*)smem;                  // 6000 B
    float* klT = (float*)(smem + 6016);        // 12864 B
    int hb = bid >> 3;
    int h = hb >> 5, b = hb & 31;
    int chunk = bid & 7;
    for (int i = tid; i < NT; i += 256) al[i] = att[(size_t)hb * NT + i];
    for (int i = tid; i < NC * NKW; i += 256)
      klT[(i % NKW) * 16 + (i / NKW)] = cw[h * NC * NKW + i];
    __syncthreads();
    int start = chunk * 188;
    int len = min(188, NT - start);
    if (tid < len) {
      int t = start + tid;
      float acc[NC];
#pragma unroll
      for (int c = 0; c < NC; ++c) acc[c] = 0.f;
      int kmin = max(0, NKS - t);
      int kmax = min(NKW - 1, NT - 1 + NKS - t);
      for (int k = kmin; k <= kmax; ++k) {
        float a = al[t + k - NKS];
        float4 w0 = *(const float4*)&klT[k * 16];
        float4 w1 = *(const float4*)&klT[k * 16 + 4];
        float2 w2 = *(const float2*)&klT[k * 16 + 8];
        acc[0] += a * w0.x; acc[1] += a * w0.y; acc[2] += a * w0.z; acc[3] += a * w0.w;
        acc[4] += a * w1.x; acc[5] += a * w1.y; acc[6] += a * w1.z; acc[7] += a * w1.w;
        acc[8] += a * w2.x; acc[9] += a * w2.y;
      }
      int row = b * NT + t;
      u16* o = cvb + ((size_t)h * NBT + row) * 32;
      short8 g0, g1, gz;
#pragma unroll
      for (int c = 0; c < 8; ++c) g0[c] = (short)f2bf(acc[c]);
      g1[0] = (short)f2bf(acc[8]); g1[1] = (short)f2bf(acc[9]);
#pragma unroll
      for (int c = 2; c < 8; ++c) g1[c] = 0;
#pragma unroll
      for (int c = 0; c < 8; ++c) gz[c] = 0;
      *(short8*)&o[0]  = g0;
      *(short8*)&o[8]  = g1;
      *(short8*)&o[16] = gz;
      *(short8*)&o[24] = gz;
    }
  } else if (bid < CV_BLKS + DP_BLKS) {
    // ---- dproj split-D: pdp[dc][h][b][a] ----
    float* z = (float*)smem;
    int id = bid - CV_BLKS;
    int hb = id >> 2, dc = id & 3;
    int h = hb >> 5, b = hb & 31;
    if (tid < 128) z[tid] = dz[b * ND + dc * 128 + tid];
    __syncthreads();
    float s = (dc == 0) ? be[h * NA + tid] : 0.f;
    const float* wp = wd + ((size_t)h * ND + dc * 128) * NA + tid;
    for (int d = 0; d < 128; ++d) s += z[d] * wp[(size_t)d * NA];
    pdp[(((size_t)dc * NH + h) * NB + b) * NA + tid] = s;
  } else if (bid < CV_BLKS + DP_BLKS + PW_BLKS) {
    // ---- W pack: wc[H][kc(68)][n(256)][8] ----
    int idx = (bid - (CV_BLKS + DP_BLKS)) * 256 + tid;
    int h = idx / 139264;
    int r = idx % 139264;
    int kc = r / 2048; r %= 2048;
    int n = r / 8;
    int j = r % 8;
    int k = kc * 8 + j;
    float v = 0.f;
    if (k < NE) v = We[((size_t)h * NE + k) * NA + n];
    else if (k - NE < NC) v = Wa[((size_t)h * NC + (k - NE)) * NA + n];
    wc[idx] = f2bf(v);
  } else {
    // ---- enc fp32 -> bf16 row-major cast (pure streaming) ----
    int id = bid - (CV_BLKS + DP_BLKS + PW_BLKS);
    size_t i0 = ((size_t)id * 256 + tid) * 16;
    const float4* s = (const float4*)(in + i0);
    float4 v0 = s[0], v1 = s[1], v2 = s[2], v3 = s[3];
    short8 a, b;
    a[0] = (short)f2bf(v0.x); a[1] = (short)f2bf(v0.y);
    a[2] = (short)f2bf(v0.z); a[3] = (short)f2bf(v0.w);
    a[4] = (short)f2bf(v1.x); a[5] = (short)f2bf(v1.y);
    a[6] = (short)f2bf(v1.z); a[7] = (short)f2bf(v1.w);
    b[0] = (short)f2bf(v2.x); b[1] = (short)f2bf(v2.y);
    b[2] = (short)f2bf(v2.z); b[3] = (short)f2bf(v2.w);
    b[4] = (short)f2bf(v3.x); b[5] = (short)f2bf(v3.y);
    b[6] = (short)f2bf(v3.z); b[7] = (short)f2bf(v3.w);
    *(short8*)(encb + i0) = a;
    *(short8*)(encb + i0 + 8) = b;
  }
}

// ---- fused GEMM + bias + tanh + gvec reduce -> e[h][b*T+t] ----
// tile 128 rows x 256 cols, BK=32 x 17 steps, 3-buffer counted-vmcnt pipeline
// A staged row-major [128][32] from row-major encb (conflict-free b128 reads)
__global__ __launch_bounds__(512) void k_gemm_e(
    const u16* __restrict__ encb, const u16* __restrict__ cvb,
    const u16* __restrict__ wcomb, const float* __restrict__ pdp,
    const float* __restrict__ gvec, float* __restrict__ ebuf) {
  // bijective XCD chunk swizzle (nwg=1500, q=187, r=4), head fastest
  const int orig = blockIdx.x;
  const int xcd = orig & 7, pos = orig >> 3;
  const int wgid = (xcd < 4 ? xcd * 188 : 752 + (xcd - 4) * 187) + pos;
  const int h = wgid & 3;
  const int rowblk = wgid >> 2;
  const int row0 = rowblk * 128;
  const int tid = threadIdx.x;
  const int lane = tid & 63;
  const int wid = tid >> 6;
  const int wm = wid >> 2;   // 0..1  (rows)
  const int wn = wid & 3;    // 0..3  (cols)
  const int l16 = lane & 15;
  const int lh = lane >> 4;

  __shared__ u16 Alds[3][4096];    // [m(128)][k(32)] row-major
  __shared__ u16 Blds[3][8192];    // [kc(4)][n(256)][8]
  __shared__ float dp[2][NA];
  __shared__ float gl[NA];
  __shared__ float elds[128][4];

  const int b0 = row0 / NT;
  const int bound = (b0 + 1) * NT - row0;   // local row where b increments
  const int b1 = min(b0 + 1, NB - 1);
  if (tid < NA) {
    float s = 0.f;
#pragma unroll
    for (int dc = 0; dc < 4; ++dc)
      s += pdp[(((size_t)dc * NH + h) * NB + b0) * NA + tid];
    dp[0][tid] = s;
    gl[tid] = gvec[h * NA + tid];
  } else {
    int a = tid - NA;
    float s = 0.f;
#pragma unroll
    for (int dc = 0; dc < 4; ++dc)
      s += pdp[(((size_t)dc * NH + h) * NB + b1) * NA + a];
    dp[1][a] = s;
  }

  f32x4 acc[4][4] = {};

  // per-thread staging sources: A row-major (row = tid>>2, 16B chunk = tid&3)
  const u16* aBase = encb + (size_t)(row0 + (tid >> 2)) * NE + (tid & 3) * 8;
  const u16* aTail = cvb + ((size_t)h * NBT + row0) * 32 + tid * 8;   // linear
  const u16* bSrc = wcomb + (size_t)h * 139264;      // [68 kc][256][8]

  const int arow = wm * 64 + l16;
  const int bcol = wn * 64 + l16;

#define ISSUE(is, buf) do {                                         \
    const u16* ga_ = ((is) < 16) ? (aBase + (is) * 32) : aTail;     \
    gld_lds16(ga_, &Alds[(buf)][tid * 8]);                          \
    const u16* gb_ = bSrc + (is) * 8192;                            \
    gld_lds16(gb_ + tid * 8, &Blds[(buf)][tid * 8]);                \
    gld_lds16(gb_ + 4096 + tid * 8, &Blds[(buf)][4096 + tid * 8]);  \
  } while (0)

  // prologue: depth-2 prefetch
  ISSUE(0, 0);
  ISSUE(1, 1);

  int cur = 0;
  for (int ks = 0; ks < 17; ++ks) {
    // wait for step ks's 3 loads (the next step's 3 stay in flight)
    if (ks < 16) asm volatile("s_waitcnt vmcnt(3)" ::: "memory");
    else         asm volatile("s_waitcnt vmcnt(0)" ::: "memory");
    __builtin_amdgcn_s_barrier();
    __builtin_amdgcn_sched_barrier(0);
    if (ks + 2 <= 16) {
      int nbuf = (cur + 2 >= 3) ? cur - 1 : cur + 2;
      ISSUE(ks + 2, nbuf);
    }
    const u16* ap = &Alds[cur][arow * 32 + lh * 8];
    const u16* bp = &Blds[cur][(lh * 256 + bcol) * 8];
    short8 af[4], bf4[4];
#pragma unroll
    for (int i = 0; i < 4; ++i) af[i] = *(const short8*)&ap[i * 512];
#pragma unroll
    for (int i = 0; i < 4; ++i) bf4[i] = *(const short8*)&bp[i * 128];
    __builtin_amdgcn_s_setprio(1);
#pragma unroll
    for (int i = 0; i < 4; ++i)
#pragma unroll
      for (int j = 0; j < 4; ++j)
        acc[i][j] = __builtin_amdgcn_mfma_f32_16x16x32_bf16(af[i], bf4[j], acc[i][j], 0, 0, 0);
    __builtin_amdgcn_s_setprio(0);
    cur = (cur == 2) ? 0 : cur + 1;
  }
#undef ISSUE
  __syncthreads();

  // epilogue: bias + fast_tanh + g-weighted col-reduce
  float ep[4][4];
#pragma unroll
  for (int i = 0; i < 4; ++i)
#pragma unroll
    for (int r = 0; r < 4; ++r) ep[i][r] = 0.f;

#pragma unroll
  for (int j = 0; j < 4; ++j) {   // col frag
    int col = wn * 64 + j * 16 + l16;
    float g = gl[col];
    float biasLo = dp[0][col], biasHi = dp[1][col];
#pragma unroll
    for (int i = 0; i < 4; ++i) {
#pragma unroll
      for (int r = 0; r < 4; ++r) {
        int rl = wm * 64 + i * 16 + lh * 4 + r;
        float bias = (rl >= bound) ? biasHi : biasLo;
        ep[i][r] += g * fast_tanh(acc[i][j][r] + bias);
      }
    }
  }
#pragma unroll
  for (int d = 1; d < 16; d <<= 1)
#pragma unroll
    for (int i = 0; i < 4; ++i)
#pragma unroll
      for (int r = 0; r < 4; ++r) ep[i][r] += __shfl_xor(ep[i][r], d, 64);

  if (l16 == 0) {
#pragma unroll
    for (int i = 0; i < 4; ++i)
#pragma unroll
      for (int r = 0; r < 4; ++r) elds[wm * 64 + i * 16 + lh * 4 + r][wn] = ep[i][r];
  }
  __syncthreads();
  if (tid < 128) {
    float e = elds[tid][0] + elds[tid][1] + elds[tid][2] + elds[tid][3];
    ebuf[(size_t)h * NBT + row0 + tid] = e;
  }
}

// ---- context with inline softmax: writes wout chunk + part[ch][h][b][e] ----
__global__ __launch_bounds__(512) void k_context(const u16* __restrict__ encb,
                                                 const float* __restrict__ ebuf,
                                                 float* __restrict__ wout,
                                                 float* __restrict__ part) {
  int b = blockIdx.x, ch = blockIdx.y;
  int tid = threadIdx.x;
  int g = tid >> 6;        // 0..7 t-subgroup
  int lane = tid & 63;     // e-chunk: e = lane*8 .. lane*8+7
  __shared__ float el[NH][NT];     // 24 KB
  __shared__ float wl[NH][192];    // 3 KB
  __shared__ float redw[NH][8];

#pragma unroll
  for (int hh = 0; hh < NH; ++hh)
    for (int t = tid; t < NT; t += 512)
      el[hh][t] = ebuf[((size_t)hh * NB + b) * NT + t];
  __syncthreads();

  // per-row max
  float mx[NH];
#pragma unroll
  for (int hh = 0; hh < NH; ++hh) {
    float m = -1e30f;
    for (int t = tid; t < NT; t += 512) m = fmaxf(m, el[hh][t]);
#pragma unroll
    for (int d = 1; d < 64; d <<= 1) m = fmaxf(m, __shfl_xor(m, d, 64));
    if (lane == 0) redw[hh][g] = m;
  }
  __syncthreads();
#pragma unroll
  for (int hh = 0; hh < NH; ++hh) {
    float m = redw[hh][0];
#pragma unroll
    for (int i = 1; i < 8; ++i) m = fmaxf(m, redw[hh][i]);
    mx[hh] = m;
  }
  __syncthreads();
  // per-row sum
  float inv[NH];
#pragma unroll
  for (int hh = 0; hh < NH; ++hh) {
    float s = 0.f;
    for (int t = tid; t < NT; t += 512) s += expf(2.f * (el[hh][t] - mx[hh]));
#pragma unroll
    for (int d = 1; d < 64; d <<= 1) s += __shfl_xor(s, d, 64);
    if (lane == 0) redw[hh][g] = s;
  }
  __syncthreads();
#pragma unroll
  for (int hh = 0; hh < NH; ++hh) {
    float s = redw[hh][0];
#pragma unroll
    for (int i = 1; i < 8; ++i) s += redw[hh][i];
    inv[hh] = 1.f / s;
  }

  int c0 = ch * 188;
  int n = min(188, NT - c0);
#pragma unroll
  for (int hh = 0; hh < NH; ++hh) {
    for (int tt = tid; tt < 188; tt += 512) {
      float w = 0.f;
      if (tt < n) {
        w = expf(2.f * (el[hh][c0 + tt] - mx[hh])) * inv[hh];
        wout[((size_t)hh * NB + b) * NT + c0 + tt] = w;
      }
      wl[hh][tt] = w;
    }
  }
  __syncthreads();

  float acc[NH][8];
#pragma unroll
  for (int hh = 0; hh < NH; ++hh)
#pragma unroll
    for (int j = 0; j < 8; ++j) acc[hh][j] = 0.f;

  for (int tt = g; tt < n; tt += 8) {
    size_t row = (size_t)b * NT + c0 + tt;
    const u16* src = encb + row * NE + lane * 8;
    short8 v = *(const short8*)src;
    float f[8];
#pragma unroll
    for (int j = 0; j < 8; ++j) f[j] = bf2f((u16)v[j]);
#pragma unroll
    for (int hh = 0; hh < NH; ++hh) {
      float ww = wl[hh][tt];
#pragma unroll
      for (int j = 0; j < 8; ++j) acc[hh][j] += ww * f[j];
    }
  }
  __shared__ float red[8][NE];   // 16 KB
#pragma unroll
  for (int hh = 0; hh < NH; ++hh) {
    __syncthreads();
#pragma unroll
    for (int j = 0; j < 8; ++j) red[g][lane * 8 + j] = acc[hh][j];
    __syncthreads();
    float s = red[0][tid] + red[1][tid] + red[2][tid] + red[3][tid]
            + red[4][tid] + red[5][tid] + red[6][tid] + red[7][tid];
    part[((size_t)(ch * NH + hh) * NB + b) * NE + tid] = s;
  }
}

// ---- out projection partials: pout[is][b][o] over i-chunk of 128 ----
__global__ __launch_bounds__(512) void k_out_part(const float* __restrict__ part,
                                                  const float* __restrict__ Wo,
                                                  float* __restrict__ pout) {
  int b = blockIdx.x, is = blockIdx.y;
  int tid = threadIdx.x;
  int i0 = is * 128;
  __shared__ float cc[128];
  if (tid < 128) {
    int i = i0 + tid;
    int hh = i >> 9, ee = i & 511;
    float s = 0.f;
#pragma unroll
    for (int ch = 0; ch < 8; ++ch)
      s += part[((size_t)(ch * NH + hh) * NB + b) * NE + ee];
    cc[tid] = s;
  }
  __syncthreads();
  float acc = 0.f;
  const float* wp = Wo + (size_t)i0 * NO + tid;
#pragma unroll 4
  for (int il = 0; il < 128; il += 4) {
    float4 v = *(const float4*)&cc[il];
    acc += v.x * wp[(size_t)(il + 0) * NO];
    acc += v.y * wp[(size_t)(il + 1) * NO];
    acc += v.z * wp[(size_t)(il + 2) * NO];
    acc += v.w * wp[(size_t)(il + 3) * NO];
  }
  pout[((size_t)is * NB + b) * NO + tid] = acc;
}

// ---- reduce out partials + bias ----
__global__ __launch_bounds__(512) void k_out_red(const float* __restrict__ pout,
                                                 const float* __restrict__ bo,
                                                 float* __restrict__ cout) {
  int b = blockIdx.x, tid = threadIdx.x;
  float acc = bo[tid];
#pragma unroll
  for (int is = 0; is < OSPLIT; ++is)
    acc += pout[((size_t)is * NB + b) * NO + tid];
  cout[(size_t)b * NO + tid] = acc;
}

extern "C" void kernel_launch(void* const* d_in, const int* in_sizes, int n_in,
                              void* d_out, int out_size, void* d_ws, size_t ws_size,
                              hipStream_t stream) {
  const float* enc      = (const float*)d_in[0];
  const float* dec_z    = (const float*)d_in[2];
  const float* att_prev = (const float*)d_in[3];
  const float* W_enc    = (const float*)d_in[4];
  const float* b_enc    = (const float*)d_in[5];
  const float* W_dec    = (const float*)d_in[6];
  const float* W_att    = (const float*)d_in[7];
  const float* conv_w   = (const float*)d_in[8];
  const float* gvec_w   = (const float*)d_in[9];
  const float* W_o      = (const float*)d_in[10];
  const float* b_o      = (const float*)d_in[11];
  float* cout = (float*)d_out;                 // [B,O]
  float* wout = (float*)d_out + NB * NO;       // [H,B,T]

  char* ws = (char*)d_ws;
  size_t off = 0;
  u16* encb   = (u16*)(ws + off); off += (size_t)NBT * NE * 2;          // 49.2 MB
  u16* cvb    = (u16*)(ws + off); off += (size_t)NH * NBT * 32 * 2;     // 12.3 MB
  u16* wcomb  = (u16*)(ws + off); off += (size_t)NH * 139264 * 2;       // 1.1 MB
  float* pdp   = (float*)(ws + off); off += (size_t)4 * NH * NB * NA * 4;
  float* ebuf  = (float*)(ws + off); off += (size_t)NH * NB * NT * 4;
  float* part  = (float*)(ws + off); off += (size_t)8 * NH * NB * NE * 4;
  float* pout  = (float*)(ws + off); off += (size_t)OSPLIT * NB * NO * 4;

  hipLaunchKernelGGL(k_prep, dim3(PREP_BLKS), dim3(256), 0, stream,
                     enc, W_enc, W_att, att_prev, conv_w, dec_z, W_dec, b_enc,
                     encb, wcomb, cvb, pdp);
  hipLaunchKernelGGL(k_gemm_e, dim3(1500), dim3(512), 0, stream,
                     encb, cvb, wcomb, pdp, gvec_w, ebuf);
  hipLaunchKernelGGL(k_context, dim3(32, 8), dim3(512), 0, stream,
                     encb, ebuf, wout, part);
  hipLaunchKernelGGL(k_out_part, dim3(NB, OSPLIT), dim3(512), 0, stream, part, W_o, pout);
  hipLaunchKernelGGL(k_out_red, dim3(NB), dim3(512), 0, stream, pout, b_o, cout);
}